// Round 7
// baseline (808.579 us; speedup 1.0000x reference)
//
#include <hip/hip_runtime.h>
#include <hip/hip_bf16.h>

#define TPB   512
#define CDIM  192
#define LDX   200   // shorts; row stride 400B
#define LDV   72    // shorts; V^T leading dim
#define SCALE 0.07216878364870323f  // 1/sqrt(192)
#define EPSF  1e-12f

using short8 = __attribute__((ext_vector_type(8))) short;
using f32x4  = __attribute__((ext_vector_type(4))) float;
using us4    = __attribute__((ext_vector_type(4))) unsigned short;

__device__ __forceinline__ unsigned short hc(float f) {
  __hip_bfloat16 h = __float2bfloat16(f);
  unsigned short u; __builtin_memcpy(&u, &h, 2); return u;
}
__device__ __forceinline__ float b2f(unsigned short h) {
  union { unsigned u; float f; } a; a.u = ((unsigned)h) << 16;
  return a.f;
}
__device__ __forceinline__ unsigned pack2(float x, float y) {
  return (unsigned)hc(x) | ((unsigned)hc(y) << 16);
}
__device__ __forceinline__ uint2 packa(f32x4 a) {
  return make_uint2(pack2(a[0], a[1]), pack2(a[2], a[3]));
}
#define MFMA(a, b, c) __builtin_amdgcn_mfma_f32_16x16x32_bf16((a), (b), (c), 0, 0, 0)

// ---- pre-kernel: cast weights f32 -> bf16 into workspace ----
#define NWQ  36864
#define NWKV 73728
#define NWP  36864
__global__ void cvt_weights(const float* __restrict__ Wq, const float* __restrict__ Wkv,
                            const float* __restrict__ Wp, unsigned short* __restrict__ o) {
  int i = blockIdx.x * blockDim.x + threadIdx.x;
  if (i < NWQ) o[i] = hc(Wq[i]);
  else if (i < NWQ + NWKV) o[i] = hc(Wkv[i - NWQ]);
  else if (i < NWQ + NWKV + NWP) o[i] = hc(Wp[i - NWQ - NWKV]);
}

__global__ __launch_bounds__(TPB, 4) void wa_v7(
    const float* __restrict__ qx, const float* __restrict__ kvx,
    const float* __restrict__ pos,
    const float* __restrict__ bq, const float* __restrict__ bkv,
    const float* __restrict__ bp,
    const unsigned short* __restrict__ Wqb, const unsigned short* __restrict__ Wkvb,
    const unsigned short* __restrict__ Wpb,
    float* __restrict__ out, int BKV)
{
  __shared__ __align__(16) unsigned short sA[64 * LDX];     // qx+pos staged -> Q -> x
  __shared__ __align__(16) unsigned short sB[64 * LDX];     // K (unnormalized)
  __shared__ __align__(16) unsigned short sVt[CDIM * LDV];  // kvx staged (flat LDX) -> V^T
  __shared__ float kinvT[6 * 64];                           // 1/||k|| per (head,row)

  const int tid = threadIdx.x;
  const int wid = tid >> 6;
  const int l15 = (tid & 63) & 15;
  const int l4  = (tid & 63) >> 4;
  const int b   = blockIdx.x;
  const size_t qoff  = (size_t)b * (64 * CDIM);
  const size_t kvoff = (size_t)(b % BKV) * (64 * CDIM);

  // paired 16-bit -> 32-bit LDS store (lanes l15 even/odd share one word)
  auto stpair = [&](unsigned short* p, unsigned short v) {
    unsigned o = (unsigned)__shfl_xor((int)(unsigned)v, 1);
    if (!(l15 & 1)) *(unsigned*)p = (unsigned)v | (o << 16);
  };

  // ============ P1: coalesced staging (qx+pos -> sA, kvx -> sVt flat) ============
  {
    const float4* gq = (const float4*)(qx + qoff);
    const float4* gk = (const float4*)(kvx + kvoff);
    const float4* p4 = (const float4*)pos;
    #pragma unroll
    for (int t = 0; t < 6; ++t) {
      int e = tid + t * TPB, row = e / 48, c4 = e % 48;
      float4 a = gq[e], p = p4[e], k = gk[e];
      us4 wq, wk;
      wq.x = hc(a.x + p.x); wq.y = hc(a.y + p.y); wq.z = hc(a.z + p.z); wq.w = hc(a.w + p.w);
      wk.x = hc(k.x); wk.y = hc(k.y); wk.z = hc(k.z); wk.w = hc(k.w);
      *(us4*)&sA[row * LDX + c4 * 4] = wq;
      *(us4*)&sVt[row * LDX + c4 * 4] = wk;
    }
  }
  __syncthreads();

  auto ptile = [&](const unsigned short* Ab, const unsigned short* Wrow0, float bv, f32x4* acc) {
    short8 B[6];
    #pragma unroll
    for (int k = 0; k < 6; ++k)
      B[k] = *(const short8*)&Wrow0[(size_t)l15 * CDIM + k * 32 + 8 * l4];
    #pragma unroll
    for (int m = 0; m < 4; ++m) acc[m] = f32x4{bv, bv, bv, bv};
    #pragma unroll
    for (int m = 0; m < 4; ++m)
      #pragma unroll
      for (int k = 0; k < 6; ++k) {
        short8 a = *(const short8*)&Ab[(16 * m + l15) * LDX + k * 32 + 8 * l4];
        acc[m] = MFMA(a, B[k], acc[m]);
      }
  };

  // ============ P2: K-proj (paired write-through sB) + V-proj (hold packs) ============
  uint2 hv1[4], hv2[4];
  {
    f32x4 acc[4];
    {
      int n = wid;
      ptile(sVt, Wkvb + (size_t)n * 16 * CDIM, bkv[n * 16 + l15], acc);
      #pragma unroll
      for (int m = 0; m < 4; ++m)
        #pragma unroll
        for (int r = 0; r < 4; ++r)
          stpair(&sB[(16 * m + 4 * l4 + r) * LDX + n * 16 + (l15 & ~1)], hc(acc[m][r]));
    }
    if (wid < 4) {
      int n = wid + 8;
      ptile(sVt, Wkvb + (size_t)n * 16 * CDIM, bkv[n * 16 + l15], acc);
      #pragma unroll
      for (int m = 0; m < 4; ++m)
        #pragma unroll
        for (int r = 0; r < 4; ++r)
          stpair(&sB[(16 * m + 4 * l4 + r) * LDX + n * 16 + (l15 & ~1)], hc(acc[m][r]));
    }
    {
      int n = wid;
      ptile(sVt, Wkvb + (size_t)(CDIM + n * 16) * CDIM, bkv[CDIM + n * 16 + l15], acc);
      #pragma unroll
      for (int m = 0; m < 4; ++m) hv1[m] = packa(acc[m]);
    }
    if (wid >= 4) {
      int n = wid + 4;
      ptile(sVt, Wkvb + (size_t)(CDIM + n * 16) * CDIM, bkv[CDIM + n * 16 + l15], acc);
      #pragma unroll
      for (int m = 0; m < 4; ++m) hv2[m] = packa(acc[m]);
    }
  }
  __syncthreads();

  // ============ P3: V^T write (b64) + Q-proj (hold packs) ============
  uint2 hq1[4], hq2[4];
  {
    #pragma unroll
    for (int m = 0; m < 4; ++m)
      *(uint2*)&sVt[(16 * wid + l15) * LDV + 16 * m + 4 * l4] = hv1[m];
    if (wid >= 4) {
      #pragma unroll
      for (int m = 0; m < 4; ++m)
        *(uint2*)&sVt[(16 * (wid + 4) + l15) * LDV + 16 * m + 4 * l4] = hv2[m];
    }
    f32x4 acc[4];
    ptile(sA, Wqb + (size_t)wid * 16 * CDIM, bq[wid * 16 + l15], acc);
    #pragma unroll
    for (int m = 0; m < 4; ++m) hq1[m] = packa(acc[m]);
    if (wid < 4) {
      int n = wid + 8;
      ptile(sA, Wqb + (size_t)n * 16 * CDIM, bq[n * 16 + l15], acc);
      #pragma unroll
      for (int m = 0; m < 4; ++m) hq2[m] = packa(acc[m]);
    }
  }
  __syncthreads();

  // ============ P4: Q write (paired words) + kinv table pass ============
  {
    auto writeQ = [&](const uint2* hq, int tile) {
      const int cb = tile * 16 + (l15 & ~1);
      #pragma unroll
      for (int m = 0; m < 4; ++m) {
        uint2 w = hq[m];
        unsigned ox = (unsigned)__shfl_xor((int)w.x, 1);
        unsigned oy = (unsigned)__shfl_xor((int)w.y, 1);
        if (!(l15 & 1)) {
          int rb = 16 * m + 4 * l4;
          *(unsigned*)&sA[(rb + 0) * LDX + cb] = (w.x & 0xffffu) | ((ox & 0xffffu) << 16);
          *(unsigned*)&sA[(rb + 1) * LDX + cb] = (w.x >> 16) | (ox & 0xffff0000u);
          *(unsigned*)&sA[(rb + 2) * LDX + cb] = (w.y & 0xffffu) | ((oy & 0xffffu) << 16);
          *(unsigned*)&sA[(rb + 3) * LDX + cb] = (w.y >> 16) | (oy & 0xffff0000u);
        }
      }
    };
    writeQ(hq1, wid);
    if (wid < 4) writeQ(hq2, wid + 8);
    if (tid < 384) {
      int h = tid >> 6, row = tid & 63;
      const unsigned short* kb = &sB[row * LDX + h * 32];
      float ss = 0.f;
      #pragma unroll
      for (int g = 0; g < 4; ++g) {
        short8 v = *(const short8*)&kb[g * 8];
        #pragma unroll
        for (int j = 0; j < 8; ++j) { float f = b2f((unsigned short)v[j]); ss += f * f; }
      }
      kinvT[tid] = 1.0f / fmaxf(sqrtf(ss), EPSF);
    }
  }
  __syncthreads();

  // ============ P5: attention (scales folded into S; barrier-free) ============
  {
    const int a_m  = wid & 3;
    const int a_hh = wid >> 2;
    const int srcA = l15 + 32 * (l4 & 1);
    const int srcB = srcA + 16;
    const int sel  = l4 >> 1;
    #pragma unroll
    for (int hp = 0; hp < 3; ++hp) {
      const int h = 2 * hp + a_hh;
      short8 bqf = *(const short8*)&sA[(16 * a_m + l15) * LDX + h * 32 + 8 * l4];
      // q-row sumsq from own frag (l15 IS the q-row; sum over l4 groups)
      float ssq = 0.f;
      #pragma unroll
      for (int j = 0; j < 8; ++j) { float f = b2f((unsigned short)bqf[j]); ssq += f * f; }
      ssq += __shfl_xor(ssq, 16);
      ssq += __shfl_xor(ssq, 32);
      const float qs = SCALE / fmaxf(sqrtf(ssq), EPSF);

      f32x4 c[4];
      #pragma unroll
      for (int n = 0; n < 4; ++n) {
        short8 ak = *(const short8*)&sB[(16 * n + l15) * LDX + h * 32 + 8 * l4];
        f32x4 z = f32x4{0.f, 0.f, 0.f, 0.f};
        c[n] = MFMA(ak, bqf, z);
      }
      #pragma unroll
      for (int n = 0; n < 4; ++n)
        #pragma unroll
        for (int r = 0; r < 4; ++r)
          c[n][r] *= qs * kinvT[h * 64 + 16 * n + 4 * l4 + r];

      float mx = c[0][0];
      #pragma unroll
      for (int n = 0; n < 4; ++n)
        #pragma unroll
        for (int r = 0; r < 4; ++r) mx = fmaxf(mx, c[n][r]);
      mx = fmaxf(mx, __shfl_xor(mx, 16));
      mx = fmaxf(mx, __shfl_xor(mx, 32));
      float sum = 0.f;
      #pragma unroll
      for (int n = 0; n < 4; ++n)
        #pragma unroll
        for (int r = 0; r < 4; ++r) { c[n][r] = __expf(c[n][r] - mx); sum += c[n][r]; }
      sum += __shfl_xor(sum, 16);
      sum += __shfl_xor(sum, 32);
      const float inv = 1.0f / sum;
      unsigned pk[4][2];
      #pragma unroll
      for (int n = 0; n < 4; ++n) {
        pk[n][0] = pack2(c[n][0] * inv, c[n][1] * inv);
        pk[n][1] = pack2(c[n][2] * inv, c[n][3] * inv);
      }
      short8 pa[2];
      #pragma unroll
      for (int cc = 0; cc < 2; ++cc) {
        unsigned a00 = (unsigned)__shfl((int)pk[2 * cc][0], srcA);
        unsigned a01 = (unsigned)__shfl((int)pk[2 * cc][1], srcA);
        unsigned a10 = (unsigned)__shfl((int)pk[2 * cc + 1][0], srcA);
        unsigned a11 = (unsigned)__shfl((int)pk[2 * cc + 1][1], srcA);
        unsigned b00 = (unsigned)__shfl((int)pk[2 * cc][0], srcB);
        unsigned b01 = (unsigned)__shfl((int)pk[2 * cc][1], srcB);
        unsigned b10 = (unsigned)__shfl((int)pk[2 * cc + 1][0], srcB);
        unsigned b11 = (unsigned)__shfl((int)pk[2 * cc + 1][1], srcB);
        union { uint4 u; short8 s; } uu;
        uu.u.x = sel ? a10 : a00;
        uu.u.y = sel ? a11 : a01;
        uu.u.z = sel ? b10 : b00;
        uu.u.w = sel ? b11 : b01;
        pa[cc] = uu.s;
      }
      #pragma unroll
      for (int n = 0; n < 2; ++n) {
        f32x4 cx = f32x4{0.f, 0.f, 0.f, 0.f};
        #pragma unroll
        for (int cc = 0; cc < 2; ++cc) {
          short8 bv = *(const short8*)&sVt[(h * 32 + 16 * n + l15) * LDV + 32 * cc + 8 * l4];
          cx = MFMA(pa[cc], bv, cx);
        }
        #pragma unroll
        for (int r = 0; r < 4; ++r)
          stpair(&sA[(16 * a_m + 4 * l4 + r) * LDX + h * 32 + 16 * n + (l15 & ~1)], hc(cx[r]));
      }
    }
  }
  __syncthreads();

  // ============ P6: out projection ============
  {
    {
      short8 B[6];
      #pragma unroll
      for (int k = 0; k < 6; ++k)
        B[k] = *(const short8*)&Wpb[(size_t)(wid * 16 + l15) * CDIM + k * 32 + 8 * l4];
      f32x4 acc[4];
      float bv = bp[wid * 16 + l15];
      #pragma unroll
      for (int m = 0; m < 4; ++m) acc[m] = f32x4{bv, bv, bv, bv};
      #pragma unroll
      for (int m = 0; m < 4; ++m)
        #pragma unroll
        for (int k = 0; k < 6; ++k) {
          short8 a = *(const short8*)&sA[(16 * m + l15) * LDX + k * 32 + 8 * l4];
          acc[m] = MFMA(a, B[k], acc[m]);
        }
      #pragma unroll
      for (int m = 0; m < 4; ++m)
        #pragma unroll
        for (int r = 0; r < 4; ++r)
          out[qoff + (size_t)(16 * m + 4 * l4 + r) * CDIM + wid * 16 + l15] = acc[m][r];
    }
    {
      const int ns = 8 + (wid >> 1);
      const int m0 = 2 * (wid & 1);
      short8 B[6];
      #pragma unroll
      for (int k = 0; k < 6; ++k)
        B[k] = *(const short8*)&Wpb[(size_t)(ns * 16 + l15) * CDIM + k * 32 + 8 * l4];
      f32x4 acc[2];
      float bv = bp[ns * 16 + l15];
      acc[0] = f32x4{bv, bv, bv, bv};
      acc[1] = f32x4{bv, bv, bv, bv};
      #pragma unroll
      for (int mm = 0; mm < 2; ++mm)
        #pragma unroll
        for (int k = 0; k < 6; ++k) {
          short8 a = *(const short8*)&sA[(16 * (m0 + mm) + l15) * LDX + k * 32 + 8 * l4];
          acc[mm] = MFMA(a, B[k], acc[mm]);
        }
      #pragma unroll
      for (int mm = 0; mm < 2; ++mm)
        #pragma unroll
        for (int r = 0; r < 4; ++r)
          out[qoff + (size_t)(16 * (m0 + mm) + 4 * l4 + r) * CDIM + ns * 16 + l15] = acc[mm][r];
    }
  }
}

extern "C" void kernel_launch(void* const* d_in, const int* in_sizes, int n_in,
                              void* d_out, int out_size, void* d_ws, size_t ws_size,
                              hipStream_t stream) {
  const float* qx  = (const float*)d_in[0];
  const float* kvx = (const float*)d_in[1];
  const float* pos = (const float*)d_in[2];
  const float* Wq  = (const float*)d_in[3];
  const float* bq  = (const float*)d_in[4];
  const float* Wkv = (const float*)d_in[5];
  const float* bkv = (const float*)d_in[6];
  const float* Wp  = (const float*)d_in[7];
  const float* bp  = (const float*)d_in[8];
  float* out = (float*)d_out;
  unsigned short* wsb = (unsigned short*)d_ws;

  const int BQ  = in_sizes[0] / (64 * CDIM);
  const int BKV = in_sizes[1] / (64 * CDIM);

  const int ncvt = NWQ + NWKV + NWP;
  cvt_weights<<<(ncvt + 255) / 256, 256, 0, stream>>>(Wq, Wkv, Wp, wsb);

  wa_v7<<<BQ, TPB, 0, stream>>>(qx, kvx, pos, bq, bkv, bp,
                                wsb, wsb + NWQ, wsb + NWQ + NWKV, out, BKV);
}